// Round 3
// baseline (338.845 us; speedup 1.0000x reference)
//
#include <hip/hip_runtime.h>
#include <stdint.h>

#define L1D 3072
#define NB 16384
#define CH 16                 // rows per chunk (per WG)
#define NCHUNK 1032           // max padded chunks: 1024 + 8 partials
#define PERM_CAP (NCHUNK * CH)

typedef float  float4v __attribute__((ext_vector_type(4)));
typedef short  short8  __attribute__((ext_vector_type(8)));

__device__ __forceinline__ unsigned short f2bf(float f) {
  uint32_t u = __builtin_bit_cast(uint32_t, f);
  u += 0x7fffu + ((u >> 16) & 1u);   // RNE; inputs finite
  return (unsigned short)(u >> 16);
}

// blocks 0..1535: combined weights W'[n][k] = l1_w[n][k] + l1f_w[n&15][k] (bf16), bias
// block 1536: bucket-sort rows -> perm[] (padded chunks of CH, pad = -1) + desc[] (chunk -> bucket)
__global__ void prep_kernel(const float* __restrict__ l1w, const float* __restrict__ l1b,
                            const float* __restrict__ l1fw, const float* __restrict__ l1fb,
                            const int* __restrict__ lsi,
                            unsigned short* __restrict__ cw, float* __restrict__ cb,
                            int* __restrict__ perm, int* __restrict__ desc) {
  if (blockIdx.x < 1536) {
    const int flat = blockIdx.x * 256 + threadIdx.x;       // 0 .. 128*3072-1
    const int n = flat / L1D;
    const int k = flat - n * L1D;
    cw[flat] = f2bf(l1w[flat] + l1fw[(n & 15) * L1D + k]);
    if (blockIdx.x == 0 && threadIdx.x < 128)
      cb[threadIdx.x] = l1b[threadIdx.x] + l1fb[threadIdx.x & 15];
    return;
  }
  // ---- sort block (single WG) ----
  __shared__ int cnt[8], base[8], padded[8], pos[8];
  const int t = threadIdx.x;
  if (t < 8) cnt[t] = 0;
  __syncthreads();
  int loc[8] = {0, 0, 0, 0, 0, 0, 0, 0};
  for (int i = 0; i < NB / 256; ++i) loc[lsi[i * 256 + t]]++;
#pragma unroll
  for (int b = 0; b < 8; ++b) if (loc[b]) atomicAdd(&cnt[b], loc[b]);
  __syncthreads();
  if (t == 0) {
    int off = 0;
    for (int b = 0; b < 8; ++b) {
      base[b] = off;
      padded[b] = (cnt[b] + CH - 1) & ~(CH - 1);
      off += padded[b];
    }
  }
  __syncthreads();
  if (t < 8) pos[t] = base[t];
  for (int i = t; i < PERM_CAP; i += 256) perm[i] = -1;
  for (int g = t; g < NCHUNK; g += 256) {
    int d = -1;
#pragma unroll
    for (int b = 0; b < 8; ++b) {
      const int c0 = base[b] / CH, c1 = (base[b] + padded[b]) / CH;
      if (g >= c0 && g < c1) d = b;
    }
    desc[g] = d;
  }
  __syncthreads();
  for (int i = 0; i < NB / 256; ++i) {
    const int r = i * 256 + t;
    const int p = atomicAdd(&pos[lsi[r]], 1);
    perm[p] = r;
  }
}

// One WG = one 16-row chunk of one bucket. No K-loop LDS, no K-loop barriers:
// A-frags straight from global (coalesced 128B row segments), B-frags from prepped bf16.
// 4 waves split K 4-way (interleaved 32-blocks); partials summed via LDS in epilogue.
__global__ __launch_bounds__(256, 2) void fused_kernel(
    const float* __restrict__ x, const unsigned short* __restrict__ cw,
    const float* __restrict__ cb, const int* __restrict__ perm, const int* __restrict__ desc,
    const float* __restrict__ gl2w, const float* __restrict__ gl2b,
    const float* __restrict__ goutw, const float* __restrict__ goutb,
    float* __restrict__ out) {
  const int b = desc[blockIdx.x];
  if (b < 0) return;                       // uniform per WG
  const int tid = threadIdx.x;
  const int lane = tid & 63;
  const int w = tid >> 6;                  // K-quarter
  const int col = lane & 15, quad = lane >> 4;

  __shared__ struct {
    float yg[4][CH][17];                   // per-K-quarter partial outputs
    float l2w[32][31];
    float l2b[32], outw[32], bias[16];
    int   prow[CH];
  } sm;

  if (tid < 32) {
    sm.l2b[tid]  = gl2b[b * 32 + tid];
    sm.outw[tid] = goutw[b * 32 + tid];
    if (tid < CH) sm.prow[tid] = perm[blockIdx.x * CH + tid];
    if (tid < 16) sm.bias[tid] = cb[b * 16 + tid];
  }
  for (int i = tid; i < 960; i += 256) {
    const int n = i / 30, k = i - n * 30;
    sm.l2w[n][k] = gl2w[(b * 32 + n) * 30 + k];
  }

  const int ri = perm[blockIdx.x * CH + col];
  const float* ap = x + (size_t)(ri < 0 ? 0 : ri) * L1D + w * 32 + quad * 8;
  const unsigned short* bp = cw + (size_t)(b * 16 + col) * L1D + w * 32 + quad * 8;

  float4v acc = {0.f, 0.f, 0.f, 0.f};
  float4v a0 = *(const float4v*)ap;
  float4v a1 = *(const float4v*)(ap + 4);
  short8  bf = *(const short8*)bp;
#pragma unroll 4
  for (int it = 0; it < 23; ++it) {        // 24 K-steps of 32 per wave (stride 128)
    const float* apn = ap + (it + 1) * 128;
    float4v na0 = *(const float4v*)apn;
    float4v na1 = *(const float4v*)(apn + 4);
    short8  nbf = *(const short8*)(bp + (it + 1) * 128);
    short8 af;
    af[0] = (short)f2bf(a0.x); af[1] = (short)f2bf(a0.y);
    af[2] = (short)f2bf(a0.z); af[3] = (short)f2bf(a0.w);
    af[4] = (short)f2bf(a1.x); af[5] = (short)f2bf(a1.y);
    af[6] = (short)f2bf(a1.z); af[7] = (short)f2bf(a1.w);
    acc = __builtin_amdgcn_mfma_f32_16x16x32_bf16(af, bf, acc, 0, 0, 0);
    a0 = na0; a1 = na1; bf = nbf;
  }
  {
    short8 af;
    af[0] = (short)f2bf(a0.x); af[1] = (short)f2bf(a0.y);
    af[2] = (short)f2bf(a0.z); af[3] = (short)f2bf(a0.w);
    af[4] = (short)f2bf(a1.x); af[5] = (short)f2bf(a1.y);
    af[6] = (short)f2bf(a1.z); af[7] = (short)f2bf(a1.w);
    acc = __builtin_amdgcn_mfma_f32_16x16x32_bf16(af, bf, acc, 0, 0, 0);
  }

  // C/D layout: D[m = quad*4+reg][n = lane&15]
#pragma unroll
  for (int rg = 0; rg < 4; ++rg) sm.yg[w][quad * 4 + rg][col] = acc[rg];
  __syncthreads();

  // tail network: 16 threads per row, 2 l2-neurons each, shuffle-reduce width 16
  {
    const int r = tid >> 4, q = tid & 15;
    const int rr = sm.prow[r];
    float act[30];
#pragma unroll
    for (int c = 0; c < 15; ++c) {
      const float v = sm.yg[0][r][c] + sm.yg[1][r][c] + sm.yg[2][r][c] + sm.yg[3][r][c]
                      + sm.bias[c];
      act[c]      = fminf(v * v * (127.0f / 128.0f), 1.0f);  // square >= 0: clip hi only
      act[15 + c] = fminf(fmaxf(v, 0.0f), 1.0f);
    }
    const float y15 = sm.yg[0][r][15] + sm.yg[1][r][15] + sm.yg[2][r][15] + sm.yg[3][r][15]
                      + sm.bias[15];
    float o = 0.0f;
#pragma unroll
    for (int nn = 0; nn < 2; ++nn) {
      const int n = q * 2 + nn;
      float s = sm.l2b[n];
#pragma unroll
      for (int k = 0; k < 30; ++k) s += act[k] * sm.l2w[n][k];
      s = fminf(fmaxf(s, 0.0f), 1.0f);
      o += s * sm.outw[n];
    }
    o += __shfl_down(o, 8, 16);
    o += __shfl_down(o, 4, 16);
    o += __shfl_down(o, 2, 16);
    o += __shfl_down(o, 1, 16);
    if (q == 0 && rr >= 0) out[rr] = o + y15 + goutb[b];
  }
}

extern "C" void kernel_launch(void* const* d_in, const int* in_sizes, int n_in,
                              void* d_out, int out_size, void* d_ws, size_t ws_size,
                              hipStream_t stream) {
  const float* x    = (const float*)d_in[0];
  const int*   lsi  = (const int*)d_in[1];
  const float* l1w  = (const float*)d_in[2];
  const float* l1b  = (const float*)d_in[3];
  const float* l1fw = (const float*)d_in[4];
  const float* l1fb = (const float*)d_in[5];
  const float* l2w  = (const float*)d_in[6];
  const float* l2b  = (const float*)d_in[7];
  const float* outw = (const float*)d_in[8];
  const float* outb = (const float*)d_in[9];
  float* out = (float*)d_out;

  unsigned short* cw = (unsigned short*)d_ws;                       // 786432 B
  float* cb  = (float*)((char*)d_ws + 786432);                      // 512 B
  int*   perm = (int*)((char*)d_ws + 786944);                       // PERM_CAP ints
  int*   desc = (int*)((char*)d_ws + 786944 + PERM_CAP * 4);        // NCHUNK ints

  prep_kernel<<<1537, 256, 0, stream>>>(l1w, l1b, l1fw, l1fb, lsi, cw, cb, perm, desc);
  fused_kernel<<<NCHUNK, 256, 0, stream>>>(x, cw, cb, perm, desc, l2w, l2b, outw, outb, out);
}

// Round 4
// 337.532 us; speedup vs baseline: 1.0039x; 1.0039x over previous
//
#include <hip/hip_runtime.h>
#include <stdint.h>

#define L1D 3072
#define NB 16384
#define CH 16                 // rows per chunk (per WG)
#define NCHUNK 1032           // max padded chunks: 1024 + 8 partials
#define PERM_CAP (NCHUNK * CH)

typedef float  float4v __attribute__((ext_vector_type(4)));
typedef short  short8  __attribute__((ext_vector_type(8)));

__device__ __forceinline__ unsigned short f2bf(float f) {
  uint32_t u = __builtin_bit_cast(uint32_t, f);
  u += 0x7fffu + ((u >> 16) & 1u);   // RNE; inputs finite
  return (unsigned short)(u >> 16);
}

// 1536 WGs: combined weights W'[n][k] = l1_w[n][k] + l1f_w[n&15][k] (bf16) + bias.
// Blocks 0..63 additionally histogram their 256-row slice of lsi (LDS reduce -> 8 global atomics).
__global__ void prep_kernel(const float* __restrict__ l1w, const float* __restrict__ l1b,
                            const float* __restrict__ l1fw, const float* __restrict__ l1fb,
                            const int* __restrict__ lsi,
                            unsigned short* __restrict__ cw, float* __restrict__ cb,
                            int* __restrict__ gcnt) {
  const int flat = blockIdx.x * 256 + threadIdx.x;       // 0 .. 128*3072-1
  const int n = flat / L1D;
  const int k = flat - n * L1D;
  cw[flat] = f2bf(l1w[flat] + l1fw[(n & 15) * L1D + k]);
  if (blockIdx.x == 0 && threadIdx.x < 128)
    cb[threadIdx.x] = l1b[threadIdx.x] + l1fb[threadIdx.x & 15];
  if (blockIdx.x < 64) {
    __shared__ int h[8];
    if (threadIdx.x < 8) h[threadIdx.x] = 0;
    __syncthreads();
    atomicAdd(&h[lsi[blockIdx.x * 256 + threadIdx.x]], 1);
    __syncthreads();
    if (threadIdx.x < 8) atomicAdd(&gcnt[threadIdx.x * 32], h[threadIdx.x]);
  }
}

// 1 WG: bucket bases from counts; desc[] chunk->bucket; init scatter cursors; pad perm slots.
__global__ void plan_kernel(const int* __restrict__ gcnt, int* __restrict__ gpos,
                            int* __restrict__ perm, int* __restrict__ desc) {
  const int t = threadIdx.x;
  int cnt[8], base[8], cb0[8], cb1[8];
  int off = 0;
#pragma unroll
  for (int b = 0; b < 8; ++b) {
    cnt[b] = gcnt[b * 32];
    base[b] = off;
    cb0[b] = off >> 4;
    off += (cnt[b] + CH - 1) & ~(CH - 1);
    cb1[b] = off >> 4;
  }
  if (t < 8) {
    gpos[t * 32] = base[t];
    const int padded = (cnt[t] + CH - 1) & ~(CH - 1);
    for (int i = cnt[t]; i < padded; ++i) perm[base[t] + i] = -1;   // <=15 pad slots/bucket
  }
  for (int g = t; g < NCHUNK; g += 256) {
    int d = -1;
#pragma unroll
    for (int b = 0; b < 8; ++b) if (g >= cb0[b] && g < cb1[b]) d = b;
    desc[g] = d;
  }
}

// 64 WGs: scatter rows into perm via padded global cursors (order within bucket irrelevant).
__global__ void scatter_kernel(const int* __restrict__ lsi, int* __restrict__ gpos,
                               int* __restrict__ perm) {
  const int r = blockIdx.x * 256 + threadIdx.x;
  const int p = atomicAdd(&gpos[lsi[r] * 32], 1);
  perm[p] = r;
}

// One WG = one 16-row chunk of one bucket. No K-loop LDS, no K-loop barriers:
// A-frags straight from global (coalesced 128B row segments), B-frags from prepped bf16.
// 4 waves split K 4-way (interleaved 32-blocks); partials summed via LDS in epilogue.
__global__ __launch_bounds__(256, 2) void fused_kernel(
    const float* __restrict__ x, const unsigned short* __restrict__ cw,
    const float* __restrict__ cb, const int* __restrict__ perm, const int* __restrict__ desc,
    const float* __restrict__ gl2w, const float* __restrict__ gl2b,
    const float* __restrict__ goutw, const float* __restrict__ goutb,
    float* __restrict__ out) {
  const int b = desc[blockIdx.x];
  if (b < 0) return;                       // uniform per WG
  const int tid = threadIdx.x;
  const int lane = tid & 63;
  const int w = tid >> 6;                  // K-quarter
  const int col = lane & 15, quad = lane >> 4;

  __shared__ struct {
    float yg[4][CH][17];                   // per-K-quarter partial outputs
    float l2w[32][31];
    float l2b[32], outw[32], bias[16];
    int   prow[CH];
  } sm;

  if (tid < 32) {
    sm.l2b[tid]  = gl2b[b * 32 + tid];
    sm.outw[tid] = goutw[b * 32 + tid];
    if (tid < CH) sm.prow[tid] = perm[blockIdx.x * CH + tid];
    if (tid < 16) sm.bias[tid] = cb[b * 16 + tid];
  }
  for (int i = tid; i < 960; i += 256) {
    const int n = i / 30, k = i - n * 30;
    sm.l2w[n][k] = gl2w[(b * 32 + n) * 30 + k];
  }

  const int ri = perm[blockIdx.x * CH + col];
  const float* ap = x + (size_t)(ri < 0 ? 0 : ri) * L1D + w * 32 + quad * 8;
  const unsigned short* bp = cw + (size_t)(b * 16 + col) * L1D + w * 32 + quad * 8;

  float4v acc = {0.f, 0.f, 0.f, 0.f};
  float4v a0 = *(const float4v*)ap;
  float4v a1 = *(const float4v*)(ap + 4);
  short8  bf = *(const short8*)bp;
#pragma unroll 4
  for (int it = 0; it < 23; ++it) {        // 24 K-steps of 32 per wave (stride 128)
    const float* apn = ap + (it + 1) * 128;
    float4v na0 = *(const float4v*)apn;
    float4v na1 = *(const float4v*)(apn + 4);
    short8  nbf = *(const short8*)(bp + (it + 1) * 128);
    short8 af;
    af[0] = (short)f2bf(a0.x); af[1] = (short)f2bf(a0.y);
    af[2] = (short)f2bf(a0.z); af[3] = (short)f2bf(a0.w);
    af[4] = (short)f2bf(a1.x); af[5] = (short)f2bf(a1.y);
    af[6] = (short)f2bf(a1.z); af[7] = (short)f2bf(a1.w);
    acc = __builtin_amdgcn_mfma_f32_16x16x32_bf16(af, bf, acc, 0, 0, 0);
    a0 = na0; a1 = na1; bf = nbf;
  }
  {
    short8 af;
    af[0] = (short)f2bf(a0.x); af[1] = (short)f2bf(a0.y);
    af[2] = (short)f2bf(a0.z); af[3] = (short)f2bf(a0.w);
    af[4] = (short)f2bf(a1.x); af[5] = (short)f2bf(a1.y);
    af[6] = (short)f2bf(a1.z); af[7] = (short)f2bf(a1.w);
    acc = __builtin_amdgcn_mfma_f32_16x16x32_bf16(af, bf, acc, 0, 0, 0);
  }

  // C/D layout: D[m = quad*4+reg][n = lane&15]
#pragma unroll
  for (int rg = 0; rg < 4; ++rg) sm.yg[w][quad * 4 + rg][col] = acc[rg];
  __syncthreads();

  // tail network: 16 threads per row, 2 l2-neurons each, shuffle-reduce width 16
  {
    const int r = tid >> 4, q = tid & 15;
    const int rr = sm.prow[r];
    float act[30];
#pragma unroll
    for (int c = 0; c < 15; ++c) {
      const float v = sm.yg[0][r][c] + sm.yg[1][r][c] + sm.yg[2][r][c] + sm.yg[3][r][c]
                      + sm.bias[c];
      act[c]      = fminf(v * v * (127.0f / 128.0f), 1.0f);  // square >= 0: clip hi only
      act[15 + c] = fminf(fmaxf(v, 0.0f), 1.0f);
    }
    const float y15 = sm.yg[0][r][15] + sm.yg[1][r][15] + sm.yg[2][r][15] + sm.yg[3][r][15]
                      + sm.bias[15];
    float o = 0.0f;
#pragma unroll
    for (int nn = 0; nn < 2; ++nn) {
      const int n = q * 2 + nn;
      float s = sm.l2b[n];
#pragma unroll
      for (int k = 0; k < 30; ++k) s += act[k] * sm.l2w[n][k];
      s = fminf(fmaxf(s, 0.0f), 1.0f);
      o += s * sm.outw[n];
    }
    o += __shfl_down(o, 8, 16);
    o += __shfl_down(o, 4, 16);
    o += __shfl_down(o, 2, 16);
    o += __shfl_down(o, 1, 16);
    if (q == 0 && rr >= 0) out[rr] = o + y15 + goutb[b];
  }
}

extern "C" void kernel_launch(void* const* d_in, const int* in_sizes, int n_in,
                              void* d_out, int out_size, void* d_ws, size_t ws_size,
                              hipStream_t stream) {
  const float* x    = (const float*)d_in[0];
  const int*   lsi  = (const int*)d_in[1];
  const float* l1w  = (const float*)d_in[2];
  const float* l1b  = (const float*)d_in[3];
  const float* l1fw = (const float*)d_in[4];
  const float* l1fb = (const float*)d_in[5];
  const float* l2w  = (const float*)d_in[6];
  const float* l2b  = (const float*)d_in[7];
  const float* outw = (const float*)d_in[8];
  const float* outb = (const float*)d_in[9];
  float* out = (float*)d_out;

  char* ws = (char*)d_ws;
  unsigned short* cw = (unsigned short*)ws;                 // 786432 B
  float* cb  = (float*)(ws + 786432);                       // 512 B
  int* gcnt  = (int*)(ws + 786944);                         // 8 x 128B-strided = 1024 B
  int* gpos  = (int*)(ws + 787968);                         // 8 x 128B-strided = 1024 B
  int* perm  = (int*)(ws + 788992);                         // PERM_CAP * 4 = 66048 B
  int* desc  = (int*)(ws + 855040);                         // NCHUNK * 4 = 4128 B

  hipMemsetAsync(gcnt, 0, 1024, stream);
  prep_kernel<<<1536, 256, 0, stream>>>(l1w, l1b, l1fw, l1fb, lsi, cw, cb, gcnt);
  plan_kernel<<<1, 256, 0, stream>>>(gcnt, gpos, perm, desc);
  scatter_kernel<<<64, 256, 0, stream>>>(lsi, gpos, perm);
  fused_kernel<<<NCHUNK, 256, 0, stream>>>(x, cw, cb, perm, desc, l2w, l2b, outw, outb, out);
}

// Round 5
// 334.252 us; speedup vs baseline: 1.0137x; 1.0098x over previous
//
#include <hip/hip_runtime.h>
#include <stdint.h>

#define L1D 3072
#define NB 16384
#define CH 16                  // rows per chunk (per WG)
#define CAP 2560               // per-bucket perm capacity (mean 2048 + 12 sigma)
#define CPB (CAP / CH)         // 160 chunks per bucket
#define NFUSED (8 * CPB)       // 1280

typedef float  float4v __attribute__((ext_vector_type(4)));
typedef short  short8  __attribute__((ext_vector_type(8)));

__device__ __forceinline__ unsigned short f2bf(float f) {
  uint32_t u = __builtin_bit_cast(uint32_t, f);
  u += 0x7fffu + ((u >> 16) & 1u);   // RNE; inputs finite
  return (unsigned short)(u >> 16);
}

// Blocks 0..1535: combined weights W'[n][k] = l1_w[n][k] + l1f_w[n&15][k] (bf16) + bias.
// Blocks 1536..1599: scatter rows into fixed per-bucket perm regions (cnt pre-zeroed by memset).
__global__ void prep_kernel(const float* __restrict__ l1w, const float* __restrict__ l1b,
                            const float* __restrict__ l1fw, const float* __restrict__ l1fb,
                            const int* __restrict__ lsi,
                            unsigned short* __restrict__ cw, float* __restrict__ cb,
                            int* __restrict__ cnt, int* __restrict__ perm) {
  if (blockIdx.x < 1536) {
    const int flat = blockIdx.x * 256 + threadIdx.x;       // 0 .. 128*3072-1
    const int n = flat / L1D;
    const int k = flat - n * L1D;
    cw[flat] = f2bf(l1w[flat] + l1fw[(n & 15) * L1D + k]);
    if (blockIdx.x == 0 && threadIdx.x < 128)
      cb[threadIdx.x] = l1b[threadIdx.x] + l1fb[threadIdx.x & 15];
  } else {
    const int r = (blockIdx.x - 1536) * 256 + threadIdx.x; // 0..16383
    const int b = lsi[r];
    const int p = atomicAdd(&cnt[b * 32], 1);              // 128B-strided counters
    perm[b * CAP + p] = r;
  }
}

// One WG = one 16-row chunk of one bucket (fixed layout: bucket = blockIdx.x/CPB).
// No K-loop LDS, no K-loop barriers: A-frags straight from global (coalesced 128B
// row segments), B-frags from prepped bf16 (L2-resident). 4 waves split K 4-way;
// partials summed via LDS once in the epilogue.
__global__ __launch_bounds__(256, 2) void fused_kernel(
    const float* __restrict__ x, const unsigned short* __restrict__ cw,
    const float* __restrict__ cb, const int* __restrict__ perm, const int* __restrict__ cnt,
    const float* __restrict__ gl2w, const float* __restrict__ gl2b,
    const float* __restrict__ goutw, const float* __restrict__ goutb,
    float* __restrict__ out) {
  const int b = blockIdx.x / CPB;
  const int local = blockIdx.x - b * CPB;
  const int cnt_b = cnt[b * 32];
  if (local * CH >= cnt_b) return;         // dead chunk (uniform per WG)
  const int tid = threadIdx.x;
  const int lane = tid & 63;
  const int w = tid >> 6;                  // K-quarter
  const int col = lane & 15, quad = lane >> 4;

  __shared__ struct {
    float yg[4][CH][17];                   // per-K-quarter partial outputs
    float l2w[32][31];
    float l2b[32], outw[32], bias[16];
    int   prow[CH];
  } sm;

  if (tid < 32) {
    sm.l2b[tid]  = gl2b[b * 32 + tid];
    sm.outw[tid] = goutw[b * 32 + tid];
    if (tid < CH)
      sm.prow[tid] = (local * CH + tid < cnt_b) ? perm[b * CAP + local * CH + tid] : -1;
    if (tid < 16) sm.bias[tid] = cb[b * 16 + tid];
  }
  for (int i = tid; i < 960; i += 256) {
    const int n = i / 30, k = i - n * 30;
    sm.l2w[n][k] = gl2w[(b * 32 + n) * 30 + k];
  }

  const int idx = local * CH + col;
  const int ri = (idx < cnt_b) ? perm[b * CAP + idx] : 0;   // inactive lanes -> row 0 (no store)
  const float* ap = x + (size_t)(ri < 0 ? 0 : ri) * L1D + w * 32 + quad * 8;
  const unsigned short* bp = cw + (size_t)(b * 16 + col) * L1D + w * 32 + quad * 8;

  float4v acc = {0.f, 0.f, 0.f, 0.f};
  float4v a0 = *(const float4v*)ap;
  float4v a1 = *(const float4v*)(ap + 4);
  short8  bf = *(const short8*)bp;
#pragma unroll 4
  for (int it = 0; it < 23; ++it) {        // 24 K-steps of 32 per wave (stride 128)
    const float* apn = ap + (it + 1) * 128;
    float4v na0 = *(const float4v*)apn;
    float4v na1 = *(const float4v*)(apn + 4);
    short8  nbf = *(const short8*)(bp + (it + 1) * 128);
    short8 af;
    af[0] = (short)f2bf(a0.x); af[1] = (short)f2bf(a0.y);
    af[2] = (short)f2bf(a0.z); af[3] = (short)f2bf(a0.w);
    af[4] = (short)f2bf(a1.x); af[5] = (short)f2bf(a1.y);
    af[6] = (short)f2bf(a1.z); af[7] = (short)f2bf(a1.w);
    acc = __builtin_amdgcn_mfma_f32_16x16x32_bf16(af, bf, acc, 0, 0, 0);
    a0 = na0; a1 = na1; bf = nbf;
  }
  {
    short8 af;
    af[0] = (short)f2bf(a0.x); af[1] = (short)f2bf(a0.y);
    af[2] = (short)f2bf(a0.z); af[3] = (short)f2bf(a0.w);
    af[4] = (short)f2bf(a1.x); af[5] = (short)f2bf(a1.y);
    af[6] = (short)f2bf(a1.z); af[7] = (short)f2bf(a1.w);
    acc = __builtin_amdgcn_mfma_f32_16x16x32_bf16(af, bf, acc, 0, 0, 0);
  }

  // C/D layout: D[m = quad*4+reg][n = lane&15]
#pragma unroll
  for (int rg = 0; rg < 4; ++rg) sm.yg[w][quad * 4 + rg][col] = acc[rg];
  __syncthreads();

  // tail network: 16 threads per row, 2 l2-neurons each, shuffle-reduce width 16
  {
    const int r = tid >> 4, q = tid & 15;
    const int rr = sm.prow[r];
    float act[30];
#pragma unroll
    for (int c = 0; c < 15; ++c) {
      const float v = sm.yg[0][r][c] + sm.yg[1][r][c] + sm.yg[2][r][c] + sm.yg[3][r][c]
                      + sm.bias[c];
      act[c]      = fminf(v * v * (127.0f / 128.0f), 1.0f);  // square >= 0: clip hi only
      act[15 + c] = fminf(fmaxf(v, 0.0f), 1.0f);
    }
    const float y15 = sm.yg[0][r][15] + sm.yg[1][r][15] + sm.yg[2][r][15] + sm.yg[3][r][15]
                      + sm.bias[15];
    float o = 0.0f;
#pragma unroll
    for (int nn = 0; nn < 2; ++nn) {
      const int n = q * 2 + nn;
      float s = sm.l2b[n];
#pragma unroll
      for (int k = 0; k < 30; ++k) s += act[k] * sm.l2w[n][k];
      s = fminf(fmaxf(s, 0.0f), 1.0f);
      o += s * sm.outw[n];
    }
    o += __shfl_down(o, 8, 16);
    o += __shfl_down(o, 4, 16);
    o += __shfl_down(o, 2, 16);
    o += __shfl_down(o, 1, 16);
    if (q == 0 && rr >= 0) out[rr] = o + y15 + goutb[b];
  }
}

extern "C" void kernel_launch(void* const* d_in, const int* in_sizes, int n_in,
                              void* d_out, int out_size, void* d_ws, size_t ws_size,
                              hipStream_t stream) {
  const float* x    = (const float*)d_in[0];
  const int*   lsi  = (const int*)d_in[1];
  const float* l1w  = (const float*)d_in[2];
  const float* l1b  = (const float*)d_in[3];
  const float* l1fw = (const float*)d_in[4];
  const float* l1fb = (const float*)d_in[5];
  const float* l2w  = (const float*)d_in[6];
  const float* l2b  = (const float*)d_in[7];
  const float* outw = (const float*)d_in[8];
  const float* outb = (const float*)d_in[9];
  float* out = (float*)d_out;

  char* ws = (char*)d_ws;
  unsigned short* cw = (unsigned short*)ws;                 // 786432 B
  float* cb  = (float*)(ws + 786432);                       // 512 B
  int* cnt   = (int*)(ws + 786944);                         // 8 x 128B-strided = 1024 B
  int* perm  = (int*)(ws + 787968);                         // 8 * CAP * 4 = 81920 B

  hipMemsetAsync(cnt, 0, 1024, stream);
  prep_kernel<<<1600, 256, 0, stream>>>(l1w, l1b, l1fw, l1fb, lsi, cw, cb, cnt, perm);
  fused_kernel<<<NFUSED, 256, 0, stream>>>(x, cw, cb, perm, cnt, l2w, l2b, outw, outb, out);
}

// Round 6
// 325.954 us; speedup vs baseline: 1.0395x; 1.0255x over previous
//
#include <hip/hip_runtime.h>
#include <stdint.h>

#define L1D 3072
#define NB 16384
#define BM 16                 // rows per WG
#define NWG (NB / BM)         // 1024
#define KW 768                // K per wave (4 waves)
#define KSTEPS 24             // 24 x 32 = 768

typedef float  float4v __attribute__((ext_vector_type(4)));
typedef short  short8  __attribute__((ext_vector_type(8)));

__device__ __forceinline__ unsigned short f2bf(float f) {
  uint32_t u = __builtin_bit_cast(uint32_t, f);
  u += 0x7fffu + ((u >> 16) & 1u);   // RNE; inputs finite
  return (unsigned short)(u >> 16);
}

// Combined weights in MFMA-B frag-swizzled layout:
// block (j = n>>4, ksg = k>>5) of 512 shorts; within block, lane = (quad = (k>>3)&3)*16 + (n&15)
// holds 8 consecutive k. A B-frag load in fused = one coalesced 1 KB global_load_dwordx4.
__global__ void prep_kernel(const float* __restrict__ l1w, const float* __restrict__ l1b,
                            const float* __restrict__ l1fw, const float* __restrict__ l1fb,
                            unsigned short* __restrict__ cw2, float* __restrict__ cb) {
  const int t = blockIdx.x * 256 + threadIdx.x;   // 0 .. 49151
  const int n = t / 384;                          // 0..127
  const int k8 = (t - n * 384) * 8;               // 0..3064 step 8
  const float* src = l1w + (size_t)n * L1D + k8;
  const float* fsrc = l1fw + (size_t)(n & 15) * L1D + k8;
  float4v w0 = *(const float4v*)src;
  float4v w1 = *(const float4v*)(src + 4);
  float4v f0 = *(const float4v*)fsrc;
  float4v f1 = *(const float4v*)(fsrc + 4);
  short8 o;
  o[0] = (short)f2bf(w0.x + f0.x); o[1] = (short)f2bf(w0.y + f0.y);
  o[2] = (short)f2bf(w0.z + f0.z); o[3] = (short)f2bf(w0.w + f0.w);
  o[4] = (short)f2bf(w1.x + f1.x); o[5] = (short)f2bf(w1.y + f1.y);
  o[6] = (short)f2bf(w1.z + f1.z); o[7] = (short)f2bf(w1.w + f1.w);
  const int j = n >> 4, colm = n & 15;
  const int ksg = k8 >> 5, quad = (k8 >> 3) & 3;
  *(short8*)&cw2[(size_t)((j * 96 + ksg) * 512 + (quad * 16 + colm) * 8)] = o;
  if (blockIdx.x == 0 && threadIdx.x < 128)
    cb[threadIdx.x] = l1b[threadIdx.x] + l1fb[threadIdx.x & 15];
}

// Dense, barrier-free: WG = 16 contiguous rows; wave w covers K in [w*768, (w+1)*768),
// all 128 output cols (8 MFMA tiles). A direct from x (HBM, contiguous row block),
// B direct from swizzled cw2 (L2-resident, coalesced). One syncthreads total.
__global__ __launch_bounds__(256, 2) void fused_kernel(
    const float* __restrict__ x, const int* __restrict__ lsi,
    const unsigned short* __restrict__ cw2, const float* __restrict__ cb,
    const float* __restrict__ gl2w, const float* __restrict__ gl2b,
    const float* __restrict__ goutw, const float* __restrict__ goutb,
    float* __restrict__ out) {
  const int tid = threadIdx.x;
  const int lane = tid & 63;
  const int w = tid >> 6;
  const int colm = lane & 15, quad = lane >> 4;
  const int rowbase = blockIdx.x * BM;

  __shared__ float yg[4][BM][130];
  __shared__ float biassm[128];
  __shared__ int   lsb[BM];

  if (tid < 128) biassm[tid] = cb[tid];
  if (tid < BM)  lsb[tid] = lsi[rowbase + tid];

  // A: lane holds row (lane&15), k = quad*8 + e  -> 8 consecutive floats
  const float* ap = x + (size_t)(rowbase + colm) * L1D + w * KW + quad * 8;
  // B: frag (j, ksg = w*24+it) at cw2 + ((j*96+ksg)*64 + lane)*8 shorts
  const unsigned short* bp = cw2 + (size_t)lane * 8;

  float4v acc[8];
#pragma unroll
  for (int j = 0; j < 8; ++j) acc[j] = float4v{0.f, 0.f, 0.f, 0.f};

  float4v a0 = *(const float4v*)ap;
  float4v a1 = *(const float4v*)(ap + 4);
  short8 bcur[8];
#pragma unroll
  for (int j = 0; j < 8; ++j)
    bcur[j] = *(const short8*)(bp + (size_t)(j * 96 + w * 24) * 512);

  for (int it = 0; it < KSTEPS; ++it) {
    float4v na0, na1;
    short8 nb[8];
    if (it + 1 < KSTEPS) {
      const float* apn = ap + (it + 1) * 32;
      na0 = *(const float4v*)apn;
      na1 = *(const float4v*)(apn + 4);
#pragma unroll
      for (int j = 0; j < 8; ++j)
        nb[j] = *(const short8*)(bp + (size_t)(j * 96 + w * 24 + it + 1) * 512);
    }
    short8 af;
    af[0] = (short)f2bf(a0.x); af[1] = (short)f2bf(a0.y);
    af[2] = (short)f2bf(a0.z); af[3] = (short)f2bf(a0.w);
    af[4] = (short)f2bf(a1.x); af[5] = (short)f2bf(a1.y);
    af[6] = (short)f2bf(a1.z); af[7] = (short)f2bf(a1.w);
#pragma unroll
    for (int j = 0; j < 8; ++j)
      acc[j] = __builtin_amdgcn_mfma_f32_16x16x32_bf16(af, bcur[j], acc[j], 0, 0, 0);
    if (it + 1 < KSTEPS) {
      a0 = na0; a1 = na1;
#pragma unroll
      for (int j = 0; j < 8; ++j) bcur[j] = nb[j];
    }
  }

  // C/D layout: D[m = quad*4+rg][n = j*16 + colm]
#pragma unroll
  for (int j = 0; j < 8; ++j)
#pragma unroll
    for (int rg = 0; rg < 4; ++rg)
      yg[w][quad * 4 + rg][j * 16 + colm] = acc[j][rg];
  __syncthreads();

  // tail: 16 threads per row, 2 l2-neurons each, shuffle-reduce width 16
  {
    const int r = tid >> 4, q = tid & 15;
    const int b = lsb[r];
    const int c0 = b * 16;
    float act[30];
#pragma unroll
    for (int c = 0; c < 15; ++c) {
      const float v = yg[0][r][c0 + c] + yg[1][r][c0 + c] + yg[2][r][c0 + c]
                      + yg[3][r][c0 + c] + biassm[c0 + c];
      act[c]      = fminf(v * v * (127.0f / 128.0f), 1.0f);  // square >= 0: clip hi only
      act[15 + c] = fminf(fmaxf(v, 0.0f), 1.0f);
    }
    const float y15 = yg[0][r][c0 + 15] + yg[1][r][c0 + 15] + yg[2][r][c0 + 15]
                      + yg[3][r][c0 + 15] + biassm[c0 + 15];
    float o = 0.0f;
#pragma unroll
    for (int nn = 0; nn < 2; ++nn) {
      const int n = q * 2 + nn;
      const float* wrow = gl2w + (size_t)(b * 32 + n) * 30;
      float s = gl2b[b * 32 + n];
#pragma unroll
      for (int k = 0; k < 30; ++k) s += act[k] * wrow[k];
      s = fminf(fmaxf(s, 0.0f), 1.0f);
      o += s * goutw[b * 32 + n];
    }
    o += __shfl_down(o, 8, 16);
    o += __shfl_down(o, 4, 16);
    o += __shfl_down(o, 2, 16);
    o += __shfl_down(o, 1, 16);
    if (q == 0) out[rowbase + r] = o + y15 + goutb[b];
  }
}

extern "C" void kernel_launch(void* const* d_in, const int* in_sizes, int n_in,
                              void* d_out, int out_size, void* d_ws, size_t ws_size,
                              hipStream_t stream) {
  const float* x    = (const float*)d_in[0];
  const int*   lsi  = (const int*)d_in[1];
  const float* l1w  = (const float*)d_in[2];
  const float* l1b  = (const float*)d_in[3];
  const float* l1fw = (const float*)d_in[4];
  const float* l1fb = (const float*)d_in[5];
  const float* l2w  = (const float*)d_in[6];
  const float* l2b  = (const float*)d_in[7];
  const float* outw = (const float*)d_in[8];
  const float* outb = (const float*)d_in[9];
  float* out = (float*)d_out;

  char* ws = (char*)d_ws;
  unsigned short* cw2 = (unsigned short*)ws;        // 768 KB swizzled combined weights
  float* cb = (float*)(ws + 786432);                // 512 B combined bias

  prep_kernel<<<192, 256, 0, stream>>>(l1w, l1b, l1fw, l1fb, cw2, cb);
  fused_kernel<<<NWG, 256, 0, stream>>>(x, lsi, cw2, cb, l2w, l2b, outw, outb, out);
}